// Round 1
// baseline (10680.705 us; speedup 1.0000x reference)
//
#include <hip/hip_runtime.h>
#include <math.h>

#define B_  4
#define S_  512
#define N_  128
#define E_  128
#define H_  120
#define R_  97
#define D_  768
#define L_  12
#define NH_ 12
#define DH_ 64
#define FF_ 3072

#define BM 64
#define BN 64
#define BK 16

// ---------------- block reduce helpers (256 threads = 4 waves) ----------------
__device__ __forceinline__ float bsum256(float v, float* sh) {
#pragma unroll
    for (int o = 32; o > 0; o >>= 1) v += __shfl_down(v, o, 64);
    int w = threadIdx.x >> 6;
    __syncthreads();
    if ((threadIdx.x & 63) == 0) sh[w] = v;
    __syncthreads();
    return sh[0] + sh[1] + sh[2] + sh[3];
}

__device__ __forceinline__ float bmax256(float v, float* sh) {
#pragma unroll
    for (int o = 32; o > 0; o >>= 1) v = fmaxf(v, __shfl_down(v, o, 64));
    int w = threadIdx.x >> 6;
    __syncthreads();
    if ((threadIdx.x & 63) == 0) sh[w] = v;
    __syncthreads();
    return fmaxf(fmaxf(sh[0], sh[1]), fmaxf(sh[2], sh[3]));
}

// ---------------- generic tiled fp32 GEMM ----------------
// C[M,N] = act(alpha * A[M,K] @ W + bias), W row-major [K,N] (TRANSW=0) or [N,K] (TRANSW=1).
// Batched over grid.z: z1=z/zdiv, z2=z%zdiv; each operand offset = z1*bs1 + z2*bs2.
// ACT: 0 none, 1 tanh, 2 exact gelu, 3 relu(x/rowdiv[row])
template <int ACT, int TRANSW>
__global__ __launch_bounds__(256) void gemm_k(
    const float* __restrict__ A, const float* __restrict__ W,
    const float* __restrict__ bias, const float* __restrict__ rowdiv,
    float* __restrict__ C, int M, int N, int K, int lda, int ldw, int ldc,
    long bsA1, long bsA2, long bsW1, long bsW2, long bsC1, long bsC2,
    int zdiv, float alpha)
{
    __shared__ float As[BK][BM];
    __shared__ float Bs[BK][BN];

    int z = blockIdx.z;
    int z1 = z / zdiv, z2 = z % zdiv;
    A += z1 * bsA1 + z2 * bsA2;
    W += z1 * bsW1 + z2 * bsW2;
    C += z1 * bsC1 + z2 * bsC2;

    int row0 = blockIdx.y * BM;
    int col0 = blockIdx.x * BN;
    int tid = threadIdx.x;
    int tx = tid & 15, ty = tid >> 4;

    float acc[4][4] = {};

    for (int k0 = 0; k0 < K; k0 += BK) {
        // A tile -> As[k][m] (transposed store)
        {
            int idx = tid * 4;
            int m = idx >> 4;
            int kk = idx & 15;
            int gr = row0 + m, gk = k0 + kk;
            float4 v = {0.f, 0.f, 0.f, 0.f};
            if (gr < M) {
                const float* ap = A + (long)gr * lda + gk;
                if (gk + 3 < K) v = *(const float4*)ap;
                else {
                    if (gk < K) v.x = ap[0];
                    if (gk + 1 < K) v.y = ap[1];
                    if (gk + 2 < K) v.z = ap[2];
                    if (gk + 3 < K) v.w = ap[3];
                }
            }
            As[kk + 0][m] = v.x; As[kk + 1][m] = v.y;
            As[kk + 2][m] = v.z; As[kk + 3][m] = v.w;
        }
        // W tile -> Bs[k][n]
        if (!TRANSW) {
            int idx = tid * 4;
            int kk = idx >> 6;
            int n = idx & 63;
            int gk = k0 + kk, gn = col0 + n;
            float4 v = {0.f, 0.f, 0.f, 0.f};
            if (gk < K) {
                const float* wp = W + (long)gk * ldw + gn;
                if (gn + 3 < N) v = *(const float4*)wp;
                else {
                    if (gn < N) v.x = wp[0];
                    if (gn + 1 < N) v.y = wp[1];
                    if (gn + 2 < N) v.z = wp[2];
                    if (gn + 3 < N) v.w = wp[3];
                }
            }
            *(float4*)&Bs[kk][n] = v;
        } else {
            int idx = tid * 4;
            int n = idx >> 4;
            int kk = idx & 15;
            int gn = col0 + n, gk = k0 + kk;
            float4 v = {0.f, 0.f, 0.f, 0.f};
            if (gn < N) {
                const float* wp = W + (long)gn * ldw + gk;
                if (gk + 3 < K) v = *(const float4*)wp;
                else {
                    if (gk < K) v.x = wp[0];
                    if (gk + 1 < K) v.y = wp[1];
                    if (gk + 2 < K) v.z = wp[2];
                    if (gk + 3 < K) v.w = wp[3];
                }
            }
            Bs[kk + 0][n] = v.x; Bs[kk + 1][n] = v.y;
            Bs[kk + 2][n] = v.z; Bs[kk + 3][n] = v.w;
        }
        __syncthreads();
#pragma unroll
        for (int kk = 0; kk < BK; ++kk) {
            float4 a4 = *(const float4*)&As[kk][ty * 4];
            float4 b4 = *(const float4*)&Bs[kk][tx * 4];
            float a[4] = {a4.x, a4.y, a4.z, a4.w};
            float b[4] = {b4.x, b4.y, b4.z, b4.w};
#pragma unroll
            for (int i = 0; i < 4; ++i)
#pragma unroll
                for (int j = 0; j < 4; ++j)
                    acc[i][j] = fmaf(a[i], b[j], acc[i][j]);
        }
        __syncthreads();
    }

#pragma unroll
    for (int i = 0; i < 4; ++i) {
        int row = row0 + ty * 4 + i;
        if (row >= M) continue;
#pragma unroll
        for (int j = 0; j < 4; ++j) {
            int col = col0 + tx * 4 + j;
            if (col >= N) continue;
            float v = acc[i][j] * alpha;
            if (bias) v += bias[col];
            if (ACT == 1) v = tanhf(v);
            else if (ACT == 2) v = 0.5f * v * (1.0f + erff(v * 0.70710678118654752f));
            else if (ACT == 3) v = fmaxf(v / rowdiv[row], 0.0f);
            C[(long)row * ldc + col] = v;
        }
    }
}

static inline void launch_gemm(hipStream_t s, int act, int transw,
    const float* A, const float* W, const float* bias, const float* rowdiv,
    float* C, int M, int N, int K, int lda, int ldw, int ldc,
    long bsA1, long bsA2, long bsW1, long bsW2, long bsC1, long bsC2,
    int nz, int zdiv, float alpha)
{
    dim3 g((N + BN - 1) / BN, (M + BM - 1) / BM, nz), b(256);
#define GL(a, t) gemm_k<a, t><<<g, b, 0, s>>>(A, W, bias, rowdiv, C, M, N, K, lda, ldw, ldc, bsA1, bsA2, bsW1, bsW2, bsC1, bsC2, zdiv, alpha)
    if (transw) {
        GL(0, 1);
    } else {
        switch (act) {
            case 0: GL(0, 0); break;
            case 1: GL(1, 0); break;
            case 2: GL(2, 0); break;
            default: GL(3, 0); break;
        }
    }
#undef GL
}

// ---------------- embedding + LN ----------------
__global__ __launch_bounds__(256) void embed_ln(
    const int* __restrict__ ids, const float* __restrict__ tok,
    const float* __restrict__ pos, const float* __restrict__ typ,
    const float* __restrict__ g, const float* __restrict__ be,
    float* __restrict__ x)
{
    int row = blockIdx.x;          // b*S + s
    int s = row & (S_ - 1);
    int id = ids[row];
    int tid = threadIdx.x;
    __shared__ float sh[4];
    float v[3];
    float sum = 0.f;
#pragma unroll
    for (int t = 0; t < 3; ++t) {
        int d = tid + t * 256;
        v[t] = tok[(long)id * D_ + d] + pos[(long)s * D_ + d] + typ[d];
        sum += v[t];
    }
    float mean = bsum256(sum, sh) * (1.0f / 768.0f);
    float q = 0.f;
#pragma unroll
    for (int t = 0; t < 3; ++t) { float dv = v[t] - mean; q += dv * dv; }
    float var = bsum256(q, sh) * (1.0f / 768.0f);
    float rstd = rsqrtf(var + 1e-12f);
    float* op = x + (long)row * D_;
#pragma unroll
    for (int t = 0; t < 3; ++t) {
        int d = tid + t * 256;
        op[d] = (v[t] - mean) * rstd * g[d] + be[d];
    }
}

// ---------------- residual + LN ----------------
__global__ __launch_bounds__(256) void ln_resid(
    float* __restrict__ out, const float* __restrict__ resid,
    const float* __restrict__ delta, const float* __restrict__ g,
    const float* __restrict__ be)
{
    long row = blockIdx.x;
    const float* rp = resid + row * D_;
    const float* dp = delta + row * D_;
    int tid = threadIdx.x;
    __shared__ float sh[4];
    float v[3];
    float sum = 0.f;
#pragma unroll
    for (int t = 0; t < 3; ++t) {
        int d = tid + t * 256;
        v[t] = rp[d] + dp[d];
        sum += v[t];
    }
    float mean = bsum256(sum, sh) * (1.0f / 768.0f);
    float q = 0.f;
#pragma unroll
    for (int t = 0; t < 3; ++t) { float dv = v[t] - mean; q += dv * dv; }
    float var = bsum256(q, sh) * (1.0f / 768.0f);
    float rstd = rsqrtf(var + 1e-12f);
    float* op = out + row * D_;
#pragma unroll
    for (int t = 0; t < 3; ++t) {
        int d = tid + t * 256;
        op[d] = (v[t] - mean) * rstd * g[d] + be[d];
    }
}

// ---------------- masked softmax over 512 ----------------
__global__ __launch_bounds__(256) void softmax512(
    float* __restrict__ sc, const float* __restrict__ mask)
{
    long row = blockIdx.x;                 // (b*NH + h)*S + i
    int b = (int)(row / (NH_ * S_));
    float* p = sc + row * S_;
    const float* mrow = mask + (long)b * S_;
    int tid = threadIdx.x;
    __shared__ float sh[4];
    float x0 = p[tid] + (1.0f - mrow[tid]) * -10000.0f;
    float x1 = p[tid + 256] + (1.0f - mrow[tid + 256]) * -10000.0f;
    float mx = bmax256(fmaxf(x0, x1), sh);
    float e0 = expf(x0 - mx), e1 = expf(x1 - mx);
    float ssum = bsum256(e0 + e1, sh);
    float inv = 1.0f / ssum;
    p[tid] = e0 * inv;
    p[tid + 256] = e1 * inv;
}

// ---------------- gather scans & fills ----------------
__global__ __launch_bounds__(512) void scan_starts(
    const int* __restrict__ starts, int* __restrict__ counts, int* __restrict__ srcidx)
{
    int b = blockIdx.x, t = threadIdx.x;
    __shared__ int pre[512];
    int sv = (starts[b * S_ + t] == 1) ? 1 : 0;
    pre[t] = sv;
    __syncthreads();
    for (int off = 1; off < 512; off <<= 1) {
        int add = (t >= off) ? pre[t - off] : 0;
        __syncthreads();
        pre[t] += add;
        __syncthreads();
    }
    if (sv) srcidx[b * S_ + pre[t] - 1] = t;
    if (t == 511) counts[b] = pre[511];
}

__global__ __launch_bounds__(256) void fill_co(
    const float* __restrict__ co, float* __restrict__ co2,
    const int* __restrict__ counts, const int* __restrict__ srcidx)
{
    int row = blockIdx.x;
    int b = row >> 9, i = row & 511;
    int cnt = counts[b];
    int maxc = max(max(counts[0], counts[1]), max(counts[2], counts[3]));
    float* d = co2 + (long)row * D_;
    if (i < cnt) {
        int s = srcidx[b * S_ + i];
        const float* src = co + (long)(b * S_ + s) * D_;
        for (int t = threadIdx.x; t < D_; t += 256) d[t] = src[t];
    } else {
        float pv = (i < maxc) ? -1.0f : 0.0f;
        for (int t = threadIdx.x; t < D_; t += 256) d[t] = pv;
    }
}

__global__ __launch_bounds__(128) void scan_nodes(
    const int* __restrict__ nmask, int* __restrict__ counts, int* __restrict__ srcidx)
{
    int b = blockIdx.x, t = threadIdx.x;
    __shared__ int pre[128];
    int sv = (nmask[b * N_ + t] == 1) ? 1 : 0;
    pre[t] = sv;
    __syncthreads();
    for (int off = 1; off < 128; off <<= 1) {
        int add = (t >= off) ? pre[t - off] : 0;
        __syncthreads();
        pre[t] += add;
        __syncthreads();
    }
    if (sv) srcidx[b * N_ + pre[t] - 1] = t;
    if (t == 127) counts[b] = pre[127];
}

__global__ __launch_bounds__(128) void fill_ent(
    const float* __restrict__ gcn, float* __restrict__ ent,
    const int* __restrict__ cnts, const int* __restrict__ src)
{
    int row = blockIdx.x;
    int b = row >> 7, i = row & 127;
    int cnt = cnts[b], t = threadIdx.x;
    float v = 0.f;
    if (i < cnt && t < H_) {
        int s = src[b * N_ + i];
        v = gcn[(long)(b * N_ + s) * H_ + t];
    }
    if (t < H_) ent[(long)row * H_ + t] = v;
}

// ---------------- row dot (root = node_rep @ lin3_w) ----------------
__global__ __launch_bounds__(256) void rowdot(
    const float* __restrict__ A, const float* __restrict__ w,
    float* __restrict__ out, int Kd)
{
    long row = blockIdx.x;
    float s = 0.f;
    for (int d = threadIdx.x; d < Kd; d += 256) s += A[row * Kd + d] * w[d];
    __shared__ float sh[4];
    s = bsum256(s, sh);
    if (threadIdx.x == 0) out[row] = s;
}

// ---------------- matrix-tree elementwise ----------------
__global__ void p_exp(float* __restrict__ P) {
    int idx = blockIdx.x * 256 + threadIdx.x;      // B*N*N
    int i = (idx >> 7) & 127, j = idx & 127;
    float v = P[idx];
    P[idx] = (i == j) ? 0.0f : expf(v);
}

__global__ __launch_bounds__(128) void colsum_k(
    const float* __restrict__ P, float* __restrict__ cs)
{
    int b = blockIdx.x, j = threadIdx.x;
    const float* p = P + (long)b * N_ * N_ + j;
    float s = 0.f;
    for (int i = 0; i < N_; ++i) s += p[i * N_];
    cs[b * N_ + j] = s;
}

__global__ void lap_build(
    const float* __restrict__ P, const float* __restrict__ cs,
    const float* __restrict__ root, float* __restrict__ lap)
{
    int idx = blockIdx.x * 256 + threadIdx.x;
    int b = idx >> 14, i = (idx >> 7) & 127, j = idx & 127;
    float v;
    if (i == 1) v = root[b * N_ + j];
    else if (i == j) v = cs[b * N_ + j];
    else v = -P[idx];
    lap[idx] = v;
}

// ---------------- in-LDS 128x128 Gauss-Jordan inverse, XOR-swizzled ----------------
__global__ __launch_bounds__(256) void invert128(
    const float* __restrict__ src, float* __restrict__ dst)
{
    __shared__ float A[128 * 128];      // 64 KiB, element (i,j) at i*128 + (j ^ (i&31))
    int b = blockIdx.x, tid = threadIdx.x;
    const float* sp = src + (long)b * 16384;
    for (int idx = tid; idx < 16384; idx += 256) {
        int i = idx >> 7, j = idx & 127;
        A[(i << 7) | (j ^ (i & 31))] = sp[idx];
    }
    __syncthreads();
    int i = tid >> 1;
    int c0 = (tid & 1) << 6;
    for (int k = 0; k < 128; ++k) {
        float pivot = A[(k << 7) | (k ^ (k & 31))];
        float f = A[(i << 7) | (k ^ (i & 31))];
        __syncthreads();
        float p = 1.0f / pivot;
        if (tid < 128) {
            int j = tid;
            int a = (k << 7) | (j ^ (k & 31));
            A[a] = (j == k) ? p : A[a] * p;
        }
        __syncthreads();
        if (i != k) {
            for (int jj = 0; jj < 64; ++jj) {
                int j = c0 + jj;
                int ai = (i << 7) | (j ^ (i & 31));
                if (j == k) A[ai] = -f * p;
                else A[ai] = fmaf(-f, A[(k << 7) | (j ^ (k & 31))], A[ai]);
            }
        }
        __syncthreads();
    }
    for (int idx = tid; idx < 16384; idx += 256) {
        int ii = idx >> 7, j = idx & 127;
        dst[(long)b * 16384 + idx] = A[(ii << 7) | (j ^ (ii & 31))];
    }
}

__global__ void edge_build(
    const float* __restrict__ t1, const float* __restrict__ t2,
    float* __restrict__ edge)
{
    int idx = blockIdx.x * 256 + threadIdx.x;
    int i = (idx >> 7) & 127, j = idx & 127;
    float v;
    if (j == 1) v = -t2[idx];
    else if (i == 1) v = t1[idx];
    else v = t1[idx] - t2[idx];
    edge[idx] = v;
}

__global__ __launch_bounds__(128) void denom_k(
    const float* __restrict__ edge, float* __restrict__ den)
{
    int b = blockIdx.x, i = threadIdx.x;
    const float* e = edge + (long)b * N_ * N_ + (long)i * N_;
    float s = 1.0f;
    for (int j = 0; j < N_; ++j) s += e[j];
    den[b * N_ + i] = s;
}

__global__ void addv(float* __restrict__ c, const float* __restrict__ a, int n) {
    int idx = blockIdx.x * 256 + threadIdx.x;
    if (idx < n) c[idx] += a[idx];
}

// ---------------- bilinear classifier: pred[b,i,j,r] = G[b,i,r,:]·ent[b,j,:] + cls_b[r] ----------------
__global__ __launch_bounds__(256) void pred_kernel(
    const float* __restrict__ G, const float* __restrict__ ent,
    const float* __restrict__ cls_b, float* __restrict__ out)
{
    int bi = blockIdx.x;                // b*N + i
    int b = bi >> 7;
    __shared__ float Gs[R_ * (H_ + 1)];  // pad stride 121 to avoid bank conflicts
    const float* gp = G + (long)bi * R_ * H_;
    for (int idx = threadIdx.x; idx < R_ * H_; idx += 256) {
        int r = idx / H_, k = idx - r * H_;
        Gs[r * (H_ + 1) + k] = gp[idx];
    }
    __syncthreads();
    long obase = (long)bi * E_ * R_;
    for (int idx = threadIdx.x; idx < E_ * R_; idx += 256) {
        int j = idx / R_, r = idx - j * R_;
        const float* e = ent + (long)(b * N_ + j) * H_;
        const float* gr = &Gs[r * (H_ + 1)];
        float s = 0.f;
#pragma unroll 8
        for (int k = 0; k < H_; ++k) s = fmaf(gr[k], e[k], s);
        out[obase + (long)j * R_ + r] = s + cls_b[r];
    }
}

// ---------------- host ----------------
extern "C" void kernel_launch(void* const* d_in, const int* in_sizes, int n_in,
                              void* d_out, int out_size, void* d_ws, size_t ws_size,
                              hipStream_t stream)
{
    (void)in_sizes; (void)n_in; (void)out_size; (void)ws_size;

    const int*   context_idxs  = (const int*)d_in[0];
    const float* context_masks = (const float*)d_in[1];
    const int*   context_starts= (const int*)d_in[2];
    const float* node_mapping  = (const float*)d_in[3];
    const int*   node_mask     = (const int*)d_in[4];
    const float* tok_emb  = (const float*)d_in[17];
    const float* pos_emb  = (const float*)d_in[18];
    const float* type_emb = (const float*)d_in[19];
    const float* emb_ln_g = (const float*)d_in[20];
    const float* emb_ln_b = (const float*)d_in[21];
    const float* q_w = (const float*)d_in[22];
    const float* q_b = (const float*)d_in[23];
    const float* k_w = (const float*)d_in[24];
    const float* k_b = (const float*)d_in[25];
    const float* v_w = (const float*)d_in[26];
    const float* v_b = (const float*)d_in[27];
    const float* o_w = (const float*)d_in[28];
    const float* o_b = (const float*)d_in[29];
    const float* attn_ln_g = (const float*)d_in[30];
    const float* attn_ln_b = (const float*)d_in[31];
    const float* f1_w = (const float*)d_in[32];
    const float* f1_b = (const float*)d_in[33];
    const float* f2_w = (const float*)d_in[34];
    const float* f2_b = (const float*)d_in[35];
    const float* ffn_ln_g = (const float*)d_in[36];
    const float* ffn_ln_b = (const float*)d_in[37];
    const float* lin1_w = (const float*)d_in[38];
    const float* lin2_w = (const float*)d_in[39];
    const float* lin3_w = (const float*)d_in[40];
    const float* induction = (const float*)d_in[41];
    const float* gcn_w0 = (const float*)d_in[42];
    const float* gcn_b0 = (const float*)d_in[43];
    const float* gcn_w1 = (const float*)d_in[44];
    const float* gcn_b1 = (const float*)d_in[45];
    const float* cls_w = (const float*)d_in[46];
    const float* cls_b = (const float*)d_in[47];

    float* ws = (float*)d_ws;
    size_t off = 0;
    auto alloc = [&](size_t n) { float* p = ws + off; off += n; return p; };

    float* X    = alloc((size_t)B_ * S_ * D_);       // 1,572,864
    float* Q    = alloc((size_t)B_ * S_ * D_);
    float* Kb   = alloc((size_t)B_ * S_ * D_);
    float* V    = alloc((size_t)B_ * S_ * D_);
    float* CTX  = alloc((size_t)B_ * S_ * D_);
    float* PROJ = alloc((size_t)B_ * S_ * D_);
    float* FFH  = alloc((size_t)B_ * S_ * FF_);      // 6,291,456
    float* SC   = alloc((size_t)B_ * NH_ * S_ * S_); // 12,582,912
    float* CO2  = alloc((size_t)B_ * S_ * D_);
    float* NR   = alloc((size_t)B_ * N_ * D_);       // 393,216
    float* H1   = alloc((size_t)B_ * N_ * H_);
    float* H2   = alloc((size_t)B_ * N_ * H_);
    float* G1   = alloc((size_t)B_ * N_ * H_);
    float* ROOT = alloc((size_t)B_ * N_);
    float* BIL  = alloc((size_t)B_ * N_ * N_);       // becomes P in place
    float* CS   = alloc((size_t)B_ * N_);
    float* LAP  = alloc((size_t)B_ * N_ * N_);
    float* INV  = alloc((size_t)B_ * N_ * N_);
    float* T1   = alloc((size_t)B_ * N_ * N_);
    float* T2   = alloc((size_t)B_ * N_ * N_);
    float* EDGE = alloc((size_t)B_ * N_ * N_);
    float* DEN  = alloc((size_t)B_ * N_);
    float* GT   = alloc((size_t)B_ * N_ * D_);
    float* X1   = alloc((size_t)B_ * N_ * H_);
    float* GT2  = alloc((size_t)B_ * N_ * H_);
    float* GCN  = alloc((size_t)B_ * N_ * H_);
    float* ENT  = alloc((size_t)B_ * N_ * H_);
    float* GB   = alloc((size_t)B_ * N_ * R_ * H_);  // 5,959,680

    int* ipool  = (int*)(ws + off);
    int* counts = ipool;
    int* srcidx = ipool + 4;
    int* ncnt   = srcidx + B_ * S_;
    int* nsrc   = ncnt + 4;

    // ---- embedding + LN ----
    embed_ln<<<B_ * S_, 256, 0, stream>>>(context_idxs, tok_emb, pos_emb, type_emb,
                                          emb_ln_g, emb_ln_b, X);

    // ---- 12 encoder layers ----
    for (int l = 0; l < L_; ++l) {
        const float* qw = q_w + (size_t)l * D_ * D_;
        const float* kw = k_w + (size_t)l * D_ * D_;
        const float* vw = v_w + (size_t)l * D_ * D_;
        const float* ow = o_w + (size_t)l * D_ * D_;

        launch_gemm(stream, 0, 0, X, qw, q_b + l * D_, nullptr, Q,
                    B_ * S_, D_, D_, D_, D_, D_, 0, 0, 0, 0, 0, 0, 1, 1, 1.0f);
        launch_gemm(stream, 0, 0, X, kw, k_b + l * D_, nullptr, Kb,
                    B_ * S_, D_, D_, D_, D_, D_, 0, 0, 0, 0, 0, 0, 1, 1, 1.0f);
        launch_gemm(stream, 0, 0, X, vw, v_b + l * D_, nullptr, V,
                    B_ * S_, D_, D_, D_, D_, D_, 0, 0, 0, 0, 0, 0, 1, 1, 1.0f);

        // scores[b,h] = Q_bh [S,DH] @ K_bh^T / 8
        launch_gemm(stream, 0, 1, Q, Kb, nullptr, nullptr, SC,
                    S_, S_, DH_, D_, D_, S_,
                    (long)S_ * D_, DH_, (long)S_ * D_, DH_,
                    (long)NH_ * S_ * S_, (long)S_ * S_,
                    B_ * NH_, NH_, 0.125f);

        softmax512<<<B_ * NH_ * S_, 256, 0, stream>>>(SC, context_masks);

        // ctx[b,:,h,:] = probs @ V_bh
        launch_gemm(stream, 0, 0, SC, V, nullptr, nullptr, CTX,
                    S_, DH_, S_, S_, D_, D_,
                    (long)NH_ * S_ * S_, (long)S_ * S_, (long)S_ * D_, DH_,
                    (long)S_ * D_, DH_,
                    B_ * NH_, NH_, 1.0f);

        launch_gemm(stream, 0, 0, CTX, ow, o_b + l * D_, nullptr, PROJ,
                    B_ * S_, D_, D_, D_, D_, D_, 0, 0, 0, 0, 0, 0, 1, 1, 1.0f);
        ln_resid<<<B_ * S_, 256, 0, stream>>>(X, X, PROJ,
                                              attn_ln_g + l * D_, attn_ln_b + l * D_);

        launch_gemm(stream, 2, 0, X, f1_w + (size_t)l * D_ * FF_, f1_b + l * FF_, nullptr, FFH,
                    B_ * S_, FF_, D_, D_, FF_, FF_, 0, 0, 0, 0, 0, 0, 1, 1, 1.0f);
        launch_gemm(stream, 0, 0, FFH, f2_w + (size_t)l * FF_ * D_, f2_b + l * D_, nullptr, PROJ,
                    B_ * S_, D_, FF_, FF_, D_, D_, 0, 0, 0, 0, 0, 0, 1, 1, 1.0f);
        ln_resid<<<B_ * S_, 256, 0, stream>>>(X, X, PROJ,
                                              ffn_ln_g + l * D_, ffn_ln_b + l * D_);
    }

    // ---- start-token gather ----
    scan_starts<<<B_, 512, 0, stream>>>(context_starts, counts, srcidx);
    fill_co<<<B_ * S_, 256, 0, stream>>>(X, CO2, counts, srcidx);

    // ---- node_rep = node_mapping @ co ----
    launch_gemm(stream, 0, 0, node_mapping, CO2, nullptr, nullptr, NR,
                N_, D_, S_, S_, D_, D_,
                (long)N_ * S_, 0, (long)S_ * D_, 0, (long)N_ * D_, 0,
                B_, 1, 1.0f);

    // ---- h1, h2, g1, root, bil ----
    launch_gemm(stream, 1, 0, NR, lin1_w, nullptr, nullptr, H1,
                B_ * N_, H_, D_, D_, H_, H_, 0, 0, 0, 0, 0, 0, 1, 1, 1.0f);
    launch_gemm(stream, 1, 0, NR, lin2_w, nullptr, nullptr, H2,
                B_ * N_, H_, D_, D_, H_, H_, 0, 0, 0, 0, 0, 0, 1, 1, 1.0f);
    launch_gemm(stream, 0, 0, H1, induction, nullptr, nullptr, G1,
                B_ * N_, H_, H_, H_, H_, H_, 0, 0, 0, 0, 0, 0, 1, 1, 1.0f);
    rowdot<<<B_ * N_, 256, 0, stream>>>(NR, lin3_w, ROOT, D_);
    launch_gemm(stream, 0, 1, G1, H2, nullptr, nullptr, BIL,
                N_, N_, H_, H_, H_, N_,
                (long)N_ * H_, 0, (long)N_ * H_, 0, (long)N_ * N_, 0,
                B_, 1, 1.0f);

    // ---- matrix-tree ----
    p_exp<<<(B_ * N_ * N_) / 256, 256, 0, stream>>>(BIL);
    colsum_k<<<B_, 128, 0, stream>>>(BIL, CS);
    lap_build<<<(B_ * N_ * N_) / 256, 256, 0, stream>>>(BIL, CS, ROOT, LAP);
    invert128<<<B_, 256, 0, stream>>>(LAP, INV);
    launch_gemm(stream, 0, 0, BIL, INV, nullptr, nullptr, T1,
                N_, N_, N_, N_, N_, N_,
                (long)N_ * N_, 0, (long)N_ * N_, 0, (long)N_ * N_, 0, B_, 1, 1.0f);
    launch_gemm(stream, 0, 1, BIL, INV, nullptr, nullptr, T2,
                N_, N_, N_, N_, N_, N_,
                (long)N_ * N_, 0, (long)N_ * N_, 0, (long)N_ * N_, 0, B_, 1, 1.0f);
    edge_build<<<(B_ * N_ * N_) / 256, 256, 0, stream>>>(T1, T2, EDGE);
    denom_k<<<B_, 128, 0, stream>>>(EDGE, DEN);

    // ---- GCN layer 0 ----
    launch_gemm(stream, 0, 0, EDGE, NR, nullptr, nullptr, GT,
                N_, D_, N_, N_, D_, D_,
                (long)N_ * N_, 0, (long)N_ * D_, 0, (long)N_ * D_, 0, B_, 1, 1.0f);
    addv<<<(B_ * N_ * D_) / 256, 256, 0, stream>>>(GT, NR, B_ * N_ * D_);
    launch_gemm(stream, 3, 0, GT, gcn_w0, gcn_b0, DEN, X1,
                B_ * N_, H_, D_, D_, H_, H_, 0, 0, 0, 0, 0, 0, 1, 1, 1.0f);

    // ---- GCN layer 1 ----
    launch_gemm(stream, 0, 0, EDGE, X1, nullptr, nullptr, GT2,
                N_, H_, N_, N_, H_, H_,
                (long)N_ * N_, 0, (long)N_ * H_, 0, (long)N_ * H_, 0, B_, 1, 1.0f);
    addv<<<(B_ * N_ * H_) / 256, 256, 0, stream>>>(GT2, X1, B_ * N_ * H_);
    launch_gemm(stream, 3, 0, GT2, gcn_w1, gcn_b1, DEN, GCN,
                B_ * N_, H_, H_, H_, H_, H_, 0, 0, 0, 0, 0, 0, 1, 1, 1.0f);

    // ---- entity gather ----
    scan_nodes<<<B_, 128, 0, stream>>>(node_mask, ncnt, nsrc);
    fill_ent<<<B_ * N_, 128, 0, stream>>>(GCN, ENT, ncnt, nsrc);

    // ---- classifier: G[b,i,r,:] = ent[b,i,:] @ cls_w[:,r,:] (batched over r) ----
    launch_gemm(stream, 0, 0, ENT, cls_w, nullptr, nullptr, GB,
                B_ * N_, H_, H_, H_, R_ * H_, R_ * H_,
                0, 0, (long)H_, 0, (long)H_, 0,
                R_, 1, 1.0f);
    pred_kernel<<<B_ * N_, 256, 0, stream>>>(GB, ENT, cls_b, (float*)d_out);
}

// Round 2
// 5296.420 us; speedup vs baseline: 2.0166x; 2.0166x over previous
//
#include <hip/hip_runtime.h>
#include <math.h>

#define B_  4
#define S_  512
#define N_  128
#define E_  128
#define H_  120
#define R_  97
#define D_  768
#define L_  12
#define NH_ 12
#define DH_ 64
#define FF_ 3072

typedef short s16x8 __attribute__((ext_vector_type(8)));
typedef float f32x4 __attribute__((ext_vector_type(4)));

__device__ __forceinline__ unsigned short f2b(float f) {
    unsigned int u = __float_as_uint(f);
    unsigned int r = (u + 0x7fffu + ((u >> 16) & 1u)) >> 16;
    return (unsigned short)r;
}
__device__ __forceinline__ float b2f(unsigned short h) {
    return __uint_as_float(((unsigned int)h) << 16);
}

// ---------------- block reduce helpers (256 threads = 4 waves) ----------------
__device__ __forceinline__ float bsum256(float v, float* sh) {
#pragma unroll
    for (int o = 32; o > 0; o >>= 1) v += __shfl_down(v, o, 64);
    int w = threadIdx.x >> 6;
    __syncthreads();
    if ((threadIdx.x & 63) == 0) sh[w] = v;
    __syncthreads();
    return sh[0] + sh[1] + sh[2] + sh[3];
}
__device__ __forceinline__ float bmax256(float v, float* sh) {
#pragma unroll
    for (int o = 32; o > 0; o >>= 1) v = fmaxf(v, __shfl_down(v, o, 64));
    int w = threadIdx.x >> 6;
    __syncthreads();
    if ((threadIdx.x & 63) == 0) sh[w] = v;
    __syncthreads();
    return fmaxf(fmaxf(sh[0], sh[1]), fmaxf(sh[2], sh[3]));
}

// ================= bf16 hi/lo split MFMA GEMM =================
// C[M,N] = act(alpha*(A@B^T-ish) + bias). A stored [M,K] k-contiguous (hi/lo planes),
// B stored [N,K] k-contiguous (hi/lo planes). 3-pass split: hh + hl + lh.
// Tile 128 x TN, BK=32, 256 threads (4 waves). M%128==0, N%TN==0, K%32==0 REQUIRED.
// OUTPAIR=0: write fp32 to Cf.  OUTPAIR=1: write bf16 hi/lo to Chi/Clo.
// ACT: 0 none, 2 exact gelu.
template <int TN, int ACT, int OUTPAIR>
__global__ __launch_bounds__(256) void mgemm(
    const unsigned short* __restrict__ Ahi, const unsigned short* __restrict__ Alo,
    const unsigned short* __restrict__ Bhi, const unsigned short* __restrict__ Blo,
    const float* __restrict__ bias,
    float* __restrict__ Cf, unsigned short* __restrict__ Chi, unsigned short* __restrict__ Clo,
    int M, int Nn, int K, int lda, int ldb, int ldc,
    long bsA1, long bsA2, long bsB1, long bsB2, long bsC1, long bsC2,
    int zdiv, float alpha)
{
    __shared__ unsigned short As[2][128 * 40];   // stride 40 (pad 32->40) to break conflicts
    __shared__ unsigned short Bs[2][TN * 40];

    int z = blockIdx.z;
    int z1 = z / zdiv, z2 = z - z1 * zdiv;
    long aoff = z1 * bsA1 + z2 * bsA2;
    long boff = z1 * bsB1 + z2 * bsB2;
    long coff = z1 * bsC1 + z2 * bsC2;
    Ahi += aoff; Alo += aoff; Bhi += boff; Blo += boff;

    int tid = threadIdx.x;
    int lane = tid & 63, wid = tid >> 6;
    int row0 = blockIdx.y * 128;
    int col0 = blockIdx.x * TN;

    constexpr int MI = (TN == 128) ? 4 : 2;
    int wr0 = (TN == 128) ? (wid & 1) * 64 : wid * 32;
    int wc0 = (TN == 128) ? (wid >> 1) * 64 : 0;

    int mlane = lane & 15, quad = lane >> 4;

    f32x4 acc[MI][4];
#pragma unroll
    for (int i = 0; i < MI; ++i)
#pragma unroll
        for (int j = 0; j < 4; ++j) acc[i][j] = (f32x4){0.f, 0.f, 0.f, 0.f};

    // A staging: 2 threads/row, 16 bf16 (32B) each
    int sra = tid >> 1, sha = tid & 1;
    const unsigned short* agh = Ahi + (long)(row0 + sra) * lda + sha * 16;
    const unsigned short* agl = Alo + (long)(row0 + sra) * lda + sha * 16;
    int aL = sra * 40 + sha * 16;

    // B staging
    int bL;
    const unsigned short *bgh, *bgl;
    if (TN == 128) {
        int srb = tid >> 1, shb = tid & 1;
        bgh = Bhi + (long)(col0 + srb) * ldb + shb * 16;
        bgl = Blo + (long)(col0 + srb) * ldb + shb * 16;
        bL = srb * 40 + shb * 16;
    } else {
        int srb = tid >> 2, shb = tid & 3;
        bgh = Bhi + (long)(col0 + srb) * ldb + shb * 8;
        bgl = Blo + (long)(col0 + srb) * ldb + shb * 8;
        bL = srb * 40 + shb * 8;
    }

    int afo[MI], bfo[4];
#pragma unroll
    for (int i = 0; i < MI; ++i) afo[i] = (wr0 + i * 16 + mlane) * 40 + quad * 8;
#pragma unroll
    for (int j = 0; j < 4; ++j) bfo[j] = (wc0 + j * 16 + mlane) * 40 + quad * 8;

    for (int k0 = 0; k0 < K; k0 += 32) {
        uint4 a0 = *(const uint4*)(agh + k0);
        uint4 a1 = *(const uint4*)(agh + k0 + 8);
        uint4 a2 = *(const uint4*)(agl + k0);
        uint4 a3 = *(const uint4*)(agl + k0 + 8);
        uint4 b0, b1, b2, b3;
        if (TN == 128) {
            b0 = *(const uint4*)(bgh + k0); b1 = *(const uint4*)(bgh + k0 + 8);
            b2 = *(const uint4*)(bgl + k0); b3 = *(const uint4*)(bgl + k0 + 8);
        } else {
            b0 = *(const uint4*)(bgh + k0); b2 = *(const uint4*)(bgl + k0);
        }
        __syncthreads();
        *(uint4*)&As[0][aL] = a0; *(uint4*)&As[0][aL + 8] = a1;
        *(uint4*)&As[1][aL] = a2; *(uint4*)&As[1][aL + 8] = a3;
        if (TN == 128) {
            *(uint4*)&Bs[0][bL] = b0; *(uint4*)&Bs[0][bL + 8] = b1;
            *(uint4*)&Bs[1][bL] = b2; *(uint4*)&Bs[1][bL + 8] = b3;
        } else {
            *(uint4*)&Bs[0][bL] = b0; *(uint4*)&Bs[1][bL] = b2;
        }
        __syncthreads();

        s16x8 aH[MI], aLr[MI], bH[4], bLr[4];
#pragma unroll
        for (int i = 0; i < MI; ++i) {
            aH[i]  = *(const s16x8*)&As[0][afo[i]];
            aLr[i] = *(const s16x8*)&As[1][afo[i]];
        }
#pragma unroll
        for (int j = 0; j < 4; ++j) {
            bH[j]  = *(const s16x8*)&Bs[0][bfo[j]];
            bLr[j] = *(const s16x8*)&Bs[1][bfo[j]];
        }
#pragma unroll
        for (int i = 0; i < MI; ++i)
#pragma unroll
            for (int j = 0; j < 4; ++j) {
                acc[i][j] = __builtin_amdgcn_mfma_f32_16x16x32_bf16(aH[i],  bH[j],  acc[i][j], 0, 0, 0);
                acc[i][j] = __builtin_amdgcn_mfma_f32_16x16x32_bf16(aH[i],  bLr[j], acc[i][j], 0, 0, 0);
                acc[i][j] = __builtin_amdgcn_mfma_f32_16x16x32_bf16(aLr[i], bH[j],  acc[i][j], 0, 0, 0);
            }
    }

#pragma unroll
    for (int i = 0; i < MI; ++i)
#pragma unroll
        for (int j = 0; j < 4; ++j) {
            int col = col0 + wc0 + j * 16 + mlane;
            float bb = bias ? bias[col] : 0.0f;
#pragma unroll
            for (int r = 0; r < 4; ++r) {
                int row = row0 + wr0 + i * 16 + quad * 4 + r;
                float v = acc[i][j][r] * alpha + bb;
                if (ACT == 2) v = 0.5f * v * (1.0f + erff(v * 0.70710678118654752f));
                long ci = coff + (long)row * ldc + col;
                if (!OUTPAIR) {
                    Cf[ci] = v;
                } else {
                    unsigned short h = f2b(v);
                    Chi[ci] = h;
                    Clo[ci] = f2b(v - b2f(h));
                }
            }
        }
}

// ---------------- weight transpose + hi/lo split (one layer, 1728 blocks) ----------------
// inputs [K,N] fp32 row-major; outputs [N,K] bf16 hi/lo planes packed into Wb.
__global__ __launch_bounds__(256) void wsplit(
    const float* __restrict__ qw, const float* __restrict__ kw,
    const float* __restrict__ vw, const float* __restrict__ ow,
    const float* __restrict__ f1, const float* __restrict__ f2,
    unsigned short* __restrict__ Wb)
{
    __shared__ float t[64][65];
    int blk = blockIdx.x;
    const float* src; int Nw, tk, tn; long obase, oLo; int ldo, rowoff;
    if (blk < 432)      { int w = blk / 144, r = blk % 144; tk = r / 12; tn = r % 12; Nw = 768;
                          src = (w == 0) ? qw : (w == 1) ? kw : vw;
                          obase = 0; oLo = 1769472; ldo = 768; rowoff = w * 768; }
    else if (blk < 576) { int r = blk - 432; tk = r / 12; tn = r % 12; Nw = 768;  src = ow;
                          obase = 3538944; oLo = 589824;  ldo = 768;  rowoff = 0; }
    else if (blk < 1152){ int r = blk - 576; tk = r / 48; tn = r % 48; Nw = 3072; src = f1;
                          obase = 4718592; oLo = 2359296; ldo = 768;  rowoff = 0; }
    else                { int r = blk - 1152; tk = r / 12; tn = r % 12; Nw = 768; src = f2;
                          obase = 9437184; oLo = 2359296; ldo = 3072; rowoff = 0; }
    int k0 = tk * 64, n0 = tn * 64;
    int tid = threadIdx.x, c = tid & 63, rq = tid >> 6;
#pragma unroll 4
    for (int p = 0; p < 16; ++p) {
        int r = p * 4 + rq;
        t[r][c] = src[(long)(k0 + r) * Nw + n0 + c];
    }
    __syncthreads();
    unsigned short* oh = Wb + obase;
    unsigned short* ol = oh + oLo;
#pragma unroll 4
    for (int p = 0; p < 16; ++p) {
        int n = p * 4 + rq;
        float v = t[c][n];
        unsigned short h = f2b(v);
        long oi = (long)(rowoff + n0 + n) * ldo + k0 + c;
        oh[oi] = h;
        ol[oi] = f2b(v - b2f(h));
    }
}

// ---------------- V transpose (head-sliced): QKV cols 1536.. -> Vt[bh*64+d][s] ----------------
__global__ __launch_bounds__(256) void vtrans(
    const unsigned short* __restrict__ qh, const unsigned short* __restrict__ ql,
    unsigned short* __restrict__ vth, unsigned short* __restrict__ vtl)
{
    int blk = blockIdx.x;                 // bh*8 + st
    int bh = blk >> 3, st = blk & 7;
    int b = bh / 12, h = bh % 12;
    __shared__ unsigned short th[64][65], tl[64][65];
    int tid = threadIdx.x, c = tid & 63, rq = tid >> 6;
    long ibase = (long)(b * 512 + st * 64) * 2304 + 1536 + h * 64;
#pragma unroll 4
    for (int p = 0; p < 16; ++p) {
        int s = p * 4 + rq;
        th[s][c] = qh[ibase + (long)s * 2304 + c];
        tl[s][c] = ql[ibase + (long)s * 2304 + c];
    }
    __syncthreads();
    long obase = (long)(bh * 64) * 512 + st * 64;
#pragma unroll 4
    for (int p = 0; p < 16; ++p) {
        int d = p * 4 + rq;
        vth[obase + (long)d * 512 + c] = th[c][d];
        vtl[obase + (long)d * 512 + c] = tl[c][d];
    }
}

// ---------------- qkv bias concat ----------------
__global__ void biascat(const float* __restrict__ qb, const float* __restrict__ kb,
                        const float* __restrict__ vb, float* __restrict__ out)
{
    int idx = blockIdx.x * 256 + threadIdx.x;
    if (idx >= 12 * 2304) return;
    int l = idx / 2304, j = idx - l * 2304;
    float v = (j < 768) ? qb[l * 768 + j] : (j < 1536) ? kb[l * 768 + j - 768] : vb[l * 768 + j - 1536];
    out[idx] = v;
}

// ---------------- generic tiled fp32 GEMM (graph section) ----------------
#define BM 64
#define BN 64
#define BK 16
template <int ACT, int TRANSW>
__global__ __launch_bounds__(256) void gemm_k(
    const float* __restrict__ A, const float* __restrict__ W,
    const float* __restrict__ bias, const float* __restrict__ rowdiv,
    float* __restrict__ C, int M, int N, int K, int lda, int ldw, int ldc,
    long bsA1, long bsA2, long bsW1, long bsW2, long bsC1, long bsC2,
    int zdiv, float alpha)
{
    __shared__ float As[BK][BM];
    __shared__ float Bs[BK][BN];
    int z = blockIdx.z;
    int z1 = z / zdiv, z2 = z % zdiv;
    A += z1 * bsA1 + z2 * bsA2;
    W += z1 * bsW1 + z2 * bsW2;
    C += z1 * bsC1 + z2 * bsC2;
    int row0 = blockIdx.y * BM;
    int col0 = blockIdx.x * BN;
    int tid = threadIdx.x;
    int tx = tid & 15, ty = tid >> 4;
    float acc[4][4] = {};
    for (int k0 = 0; k0 < K; k0 += BK) {
        {
            int idx = tid * 4;
            int m = idx >> 4, kk = idx & 15;
            int gr = row0 + m, gk = k0 + kk;
            float4 v = {0.f, 0.f, 0.f, 0.f};
            if (gr < M) {
                const float* ap = A + (long)gr * lda + gk;
                if (gk + 3 < K) v = *(const float4*)ap;
                else {
                    if (gk < K) v.x = ap[0];
                    if (gk + 1 < K) v.y = ap[1];
                    if (gk + 2 < K) v.z = ap[2];
                    if (gk + 3 < K) v.w = ap[3];
                }
            }
            As[kk + 0][m] = v.x; As[kk + 1][m] = v.y;
            As[kk + 2][m] = v.z; As[kk + 3][m] = v.w;
        }
        if (!TRANSW) {
            int idx = tid * 4;
            int kk = idx >> 6, n = idx & 63;
            int gk = k0 + kk, gn = col0 + n;
            float4 v = {0.f, 0.f, 0.f, 0.f};
            if (gk < K) {
                const float* wp = W + (long)gk * ldw + gn;
                if (gn + 3 < N) v = *(const float4*)wp;
                else {
                    if (gn < N) v.x = wp[0];
                    if (gn + 1 < N) v.y = wp[1];
                    if (gn + 2 < N) v.z = wp[2];
                    if (gn + 3 < N) v.w = wp[3];
                }
            }
            *(float4*)&Bs[kk][n] = v;
        } else {
            int idx = tid * 4;
            int n = idx >> 4, kk = idx & 15;
            int gn = col0 + n, gk = k0 + kk;
            float4 v = {0.f, 0.f, 0.f, 0.f};
            if (gn < N) {
                const float* wp = W + (long)gn * ldw + gk;
                if (gk + 3 < K) v = *(const float4*)wp;
                else {
                    if (gk < K) v.x = wp[0];
                    if (gk + 1 < K) v.y = wp[1];
                    if (gk + 2 < K) v.z = wp[2];
                    if (gk + 3 < K) v.w = wp[3];
                }
            }
            Bs[kk + 0][n] = v.x; Bs[kk + 1][n] = v.y;
            Bs[kk + 2][n] = v.z; Bs[kk + 3][n] = v.w;
        }
        __syncthreads();
#pragma unroll
        for (int kk = 0; kk < BK; ++kk) {
            float4 a4 = *(const float4*)&As[kk][ty * 4];
            float4 b4 = *(const float4*)&Bs[kk][tx * 4];
            float a[4] = {a4.x, a4.y, a4.z, a4.w};
            float b[4] = {b4.x, b4.y, b4.z, b4.w};
#pragma unroll
            for (int i = 0; i < 4; ++i)
#pragma unroll
                for (int j = 0; j < 4; ++j)
                    acc[i][j] = fmaf(a[i], b[j], acc[i][j]);
        }
        __syncthreads();
    }
#pragma unroll
    for (int i = 0; i < 4; ++i) {
        int row = row0 + ty * 4 + i;
        if (row >= M) continue;
#pragma unroll
        for (int j = 0; j < 4; ++j) {
            int col = col0 + tx * 4 + j;
            if (col >= N) continue;
            float v = acc[i][j] * alpha;
            if (bias) v += bias[col];
            if (ACT == 1) v = tanhf(v);
            else if (ACT == 2) v = 0.5f * v * (1.0f + erff(v * 0.70710678118654752f));
            else if (ACT == 3) v = fmaxf(v / rowdiv[row], 0.0f);
            C[(long)row * ldc + col] = v;
        }
    }
}

static inline void launch_gemm(hipStream_t s, int act, int transw,
    const float* A, const float* W, const float* bias, const float* rowdiv,
    float* C, int M, int N, int K, int lda, int ldw, int ldc,
    long bsA1, long bsA2, long bsW1, long bsW2, long bsC1, long bsC2,
    int nz, int zdiv, float alpha)
{
    dim3 g((N + BN - 1) / BN, (M + BM - 1) / BM, nz), b(256);
#define GL(a, t) gemm_k<a, t><<<g, b, 0, s>>>(A, W, bias, rowdiv, C, M, N, K, lda, ldw, ldc, bsA1, bsA2, bsW1, bsW2, bsC1, bsC2, zdiv, alpha)
    if (transw) { GL(0, 1); }
    else {
        switch (act) {
            case 0: GL(0, 0); break;
            case 1: GL(1, 0); break;
            case 2: GL(2, 0); break;
            default: GL(3, 0); break;
        }
    }
#undef GL
}

// ---------------- embedding + LN (fp32 out + bf16 hi/lo out) ----------------
__global__ __launch_bounds__(256) void embed_ln(
    const int* __restrict__ ids, const float* __restrict__ tok,
    const float* __restrict__ pos, const float* __restrict__ typ,
    const float* __restrict__ g, const float* __restrict__ be,
    float* __restrict__ x, unsigned short* __restrict__ xh, unsigned short* __restrict__ xl)
{
    int row = blockIdx.x;
    int s = row & (S_ - 1);
    int id = ids[row];
    int tid = threadIdx.x;
    __shared__ float sh[4];
    float v[3];
    float sum = 0.f;
#pragma unroll
    for (int t = 0; t < 3; ++t) {
        int d = tid + t * 256;
        v[t] = tok[(long)id * D_ + d] + pos[(long)s * D_ + d] + typ[d];
        sum += v[t];
    }
    float mean = bsum256(sum, sh) * (1.0f / 768.0f);
    float q = 0.f;
#pragma unroll
    for (int t = 0; t < 3; ++t) { float dv = v[t] - mean; q += dv * dv; }
    float var = bsum256(q, sh) * (1.0f / 768.0f);
    float rstd = rsqrtf(var + 1e-12f);
    long base = (long)row * D_;
#pragma unroll
    for (int t = 0; t < 3; ++t) {
        int d = tid + t * 256;
        float o = (v[t] - mean) * rstd * g[d] + be[d];
        x[base + d] = o;
        unsigned short h = f2b(o);
        xh[base + d] = h;
        xl[base + d] = f2b(o - b2f(h));
    }
}

// ---------------- residual + LN (fp32 out + bf16 pair out) ----------------
__global__ __launch_bounds__(256) void ln_residb(
    float* __restrict__ out, unsigned short* __restrict__ xh, unsigned short* __restrict__ xl,
    const float* __restrict__ resid, const float* __restrict__ delta,
    const float* __restrict__ g, const float* __restrict__ be)
{
    long row = blockIdx.x;
    const float* rp = resid + row * D_;
    const float* dp = delta + row * D_;
    int tid = threadIdx.x;
    __shared__ float sh[4];
    float v[3];
    float sum = 0.f;
#pragma unroll
    for (int t = 0; t < 3; ++t) {
        int d = tid + t * 256;
        v[t] = rp[d] + dp[d];
        sum += v[t];
    }
    float mean = bsum256(sum, sh) * (1.0f / 768.0f);
    float q = 0.f;
#pragma unroll
    for (int t = 0; t < 3; ++t) { float dv = v[t] - mean; q += dv * dv; }
    float var = bsum256(q, sh) * (1.0f / 768.0f);
    float rstd = rsqrtf(var + 1e-12f);
    long base = row * D_;
#pragma unroll
    for (int t = 0; t < 3; ++t) {
        int d = tid + t * 256;
        float o = (v[t] - mean) * rstd * g[d] + be[d];
        out[base + d] = o;
        unsigned short h = f2b(o);
        xh[base + d] = h;
        xl[base + d] = f2b(o - b2f(h));
    }
}

// ---------------- masked softmax over 512 -> bf16 hi/lo pairs (in-row layout [512 hi | 512 lo]) ----------------
__global__ __launch_bounds__(256) void softmax512b(
    const float* __restrict__ sc, const float* __restrict__ mask,
    unsigned short* __restrict__ outp)
{
    long row = blockIdx.x;                 // (b*NH + h)*S + i
    int b = (int)(row / (NH_ * S_));
    const float* p = sc + row * S_;
    const float* mrow = mask + (long)b * S_;
    int tid = threadIdx.x;
    __shared__ float sh[4];
    float x0 = p[tid] + (1.0f - mrow[tid]) * -10000.0f;
    float x1 = p[tid + 256] + (1.0f - mrow[tid + 256]) * -10000.0f;
    float mx = bmax256(fmaxf(x0, x1), sh);
    float e0 = expf(x0 - mx), e1 = expf(x1 - mx);
    float ssum = bsum256(e0 + e1, sh);
    float inv = 1.0f / ssum;
    e0 *= inv; e1 *= inv;
    unsigned short* o = outp + row * 1024;
    unsigned short h0 = f2b(e0), h1 = f2b(e1);
    o[tid] = h0;         o[tid + 256] = h1;
    o[512 + tid] = f2b(e0 - b2f(h0));
    o[512 + tid + 256] = f2b(e1 - b2f(h1));
}

// ---------------- gather scans & fills ----------------
__global__ __launch_bounds__(512) void scan_starts(
    const int* __restrict__ starts, int* __restrict__ counts, int* __restrict__ srcidx)
{
    int b = blockIdx.x, t = threadIdx.x;
    __shared__ int pre[512];
    int sv = (starts[b * S_ + t] == 1) ? 1 : 0;
    pre[t] = sv;
    __syncthreads();
    for (int off = 1; off < 512; off <<= 1) {
        int add = (t >= off) ? pre[t - off] : 0;
        __syncthreads();
        pre[t] += add;
        __syncthreads();
    }
    if (sv) srcidx[b * S_ + pre[t] - 1] = t;
    if (t == 511) counts[b] = pre[511];
}

__global__ __launch_bounds__(256) void fill_co(
    const float* __restrict__ co, float* __restrict__ co2,
    const int* __restrict__ counts, const int* __restrict__ srcidx)
{
    int row = blockIdx.x;
    int b = row >> 9, i = row & 511;
    int cnt = counts[b];
    int maxc = max(max(counts[0], counts[1]), max(counts[2], counts[3]));
    float* d = co2 + (long)row * D_;
    if (i < cnt) {
        int s = srcidx[b * S_ + i];
        const float* src = co + (long)(b * S_ + s) * D_;
        for (int t = threadIdx.x; t < D_; t += 256) d[t] = src[t];
    } else {
        float pv = (i < maxc) ? -1.0f : 0.0f;
        for (int t = threadIdx.x; t < D_; t += 256) d[t] = pv;
    }
}

__global__ __launch_bounds__(128) void scan_nodes(
    const int* __restrict__ nmask, int* __restrict__ counts, int* __restrict__ srcidx)
{
    int b = blockIdx.x, t = threadIdx.x;
    __shared__ int pre[128];
    int sv = (nmask[b * N_ + t] == 1) ? 1 : 0;
    pre[t] = sv;
    __syncthreads();
    for (int off = 1; off < 128; off <<= 1) {
        int add = (t >= off) ? pre[t - off] : 0;
        __syncthreads();
        pre[t] += add;
        __syncthreads();
    }
    if (sv) srcidx[b * N_ + pre[t] - 1] = t;
    if (t == 127) counts[b] = pre[127];
}

__global__ __launch_bounds__(128) void fill_ent(
    const float* __restrict__ gcn, float* __restrict__ ent,
    const int* __restrict__ cnts, const int* __restrict__ src)
{
    int row = blockIdx.x;
    int b = row >> 7, i = row & 127;
    int cnt = cnts[b], t = threadIdx.x;
    float v = 0.f;
    if (i < cnt && t < H_) {
        int s = src[b * N_ + i];
        v = gcn[(long)(b * N_ + s) * H_ + t];
    }
    if (t < H_) ent[(long)row * H_ + t] = v;
}

// ---------------- row dot ----------------
__global__ __launch_bounds__(256) void rowdot(
    const float* __restrict__ A, const float* __restrict__ w,
    float* __restrict__ out, int Kd)
{
    long row = blockIdx.x;
    float s = 0.f;
    for (int d = threadIdx.x; d < Kd; d += 256) s += A[row * Kd + d] * w[d];
    __shared__ float sh[4];
    s = bsum256(s, sh);
    if (threadIdx.x == 0) out[row] = s;
}

// ---------------- matrix-tree elementwise ----------------
__global__ void p_exp(float* __restrict__ P) {
    int idx = blockIdx.x * 256 + threadIdx.x;
    int i = (idx >> 7) & 127, j = idx & 127;
    float v = P[idx];
    P[idx] = (i == j) ? 0.0f : expf(v);
}

__global__ __launch_bounds__(128) void colsum_k(
    const float* __restrict__ P, float* __restrict__ cs)
{
    int b = blockIdx.x, j = threadIdx.x;
    const float* p = P + (long)b * N_ * N_ + j;
    float s = 0.f;
    for (int i = 0; i < N_; ++i) s += p[i * N_];
    cs[b * N_ + j] = s;
}

__global__ void lap_build(
    const float* __restrict__ P, const float* __restrict__ cs,
    const float* __restrict__ root, float* __restrict__ lap)
{
    int idx = blockIdx.x * 256 + threadIdx.x;
    int b = idx >> 14, i = (idx >> 7) & 127, j = idx & 127;
    float v;
    if (i == 1) v = root[b * N_ + j];
    else if (i == j) v = cs[b * N_ + j];
    else v = -P[idx];
    lap[idx] = v;
}

// ---------------- fp64 register-resident 128x128 Gauss-Jordan inverse ----------------
// 1024 threads: thread t owns row i=t>>3, 16-col chunk c=(t&7)*16 in registers (doubles).
__global__ __launch_bounds__(1024) void invert128d(
    const float* __restrict__ src, float* __restrict__ dst)
{
    __shared__ double prow[128];
    __shared__ double fcol[128];
    int b = blockIdx.x, t = threadIdx.x;
    int i = t >> 3, c = (t & 7) << 4;
    double d[16];
    const float* sp = src + (long)b * 16384 + i * 128 + c;
#pragma unroll
    for (int j = 0; j < 16; ++j) d[j] = (double)sp[j];
    for (int k = 0; k < 128; ++k) {
        if (k >= c && k < c + 16) fcol[i] = d[k - c];
        __syncthreads();
        double rp = 1.0 / fcol[k];
        double f = fcol[i];
        if (i == k) {
#pragma unroll
            for (int j = 0; j < 16; ++j) {
                double s = d[j] * rp;
                prow[c + j] = s;
                d[j] = (c + j == k) ? rp : s;
            }
        }
        __syncthreads();
        if (i != k) {
#pragma unroll
            for (int j = 0; j < 16; ++j) {
                d[j] = (c + j == k) ? (-f * rp) : (d[j] - f * prow[c + j]);
            }
        }
    }
    float* dp = dst + (long)b * 16384 + i * 128 + c;
#pragma unroll
    for (int j = 0; j < 16; ++j) dp[j] = (float)d[j];
}

__global__ void edge_build(
    const float* __restrict__ t1, const float* __restrict__ t2,
    float* __restrict__ edge)
{
    int idx = blockIdx.x * 256 + threadIdx.x;
    int i = (idx >> 7) & 127, j = idx & 127;
    float v;
    if (j == 1) v = -t2[idx];
    else if (i == 1) v = t1[idx];
    else v = t1[idx] - t2[idx];
    edge[idx] = v;
}

__global__ __launch_bounds__(128) void denom_k(
    const float* __restrict__ edge, float* __restrict__ den)
{
    int b = blockIdx.x, i = threadIdx.x;
    const float* e = edge + (long)b * N_ * N_ + (long)i * N_;
    float s = 1.0f;
    for (int j = 0; j < N_; ++j) s += e[j];
    den[b * N_ + i] = s;
}

__global__ void addv(float* __restrict__ c, const float* __restrict__ a, int n) {
    int idx = blockIdx.x * 256 + threadIdx.x;
    if (idx < n) c[idx] += a[idx];
}

// ---------------- bilinear classifier ----------------
__global__ __launch_bounds__(256) void pred_kernel(
    const float* __restrict__ G, const float* __restrict__ ent,
    const float* __restrict__ cls_b, float* __restrict__ out)
{
    int bi = blockIdx.x;
    int b = bi >> 7;
    __shared__ float Gs[R_ * (H_ + 1)];
    const float* gp = G + (long)bi * R_ * H_;
    for (int idx = threadIdx.x; idx < R_ * H_; idx += 256) {
        int r = idx / H_, k = idx - r * H_;
        Gs[r * (H_ + 1) + k] = gp[idx];
    }
    __syncthreads();
    long obase = (long)bi * E_ * R_;
    for (int idx = threadIdx.x; idx < E_ * R_; idx += 256) {
        int j = idx / R_, r = idx - j * R_;
        const float* e = ent + (long)(b * N_ + j) * H_;
        const float* gr = &Gs[r * (H_ + 1)];
        float s = 0.f;
#pragma unroll 8
        for (int k = 0; k < H_; ++k) s = fmaf(gr[k], e[k], s);
        out[obase + (long)j * R_ + r] = s + cls_b[r];
    }
}

// ---------------- host ----------------
extern "C" void kernel_launch(void* const* d_in, const int* in_sizes, int n_in,
                              void* d_out, int out_size, void* d_ws, size_t ws_size,
                              hipStream_t stream)
{
    (void)in_sizes; (void)n_in; (void)out_size; (void)ws_size;

    const int*   context_idxs  = (const int*)d_in[0];
    const float* context_masks = (const float*)d_in[1];
    const int*   context_starts= (const int*)d_in[2];
    const float* node_mapping  = (const float*)d_in[3];
    const int*   node_mask     = (const int*)d_in[4];
    const float* tok_emb  = (const float*)d_in[17];
    const float* pos_emb  = (const float*)d_in[18];
    const float* type_emb = (const float*)d_in[19];
    const float* emb_ln_g = (const float*)d_in[20];
    const float* emb_ln_b = (const float*)d_in[21];
    const float* q_w = (const float*)d_in[22];
    const float* q_b = (const float*)d_in[23];
    const float* k_w = (const float*)d_in[24];
    const float* k_b = (const float*)d_in[25];
    const float* v_w = (const float*)d_in[26];
    const float* v_b = (const float*)d_in[27];
    const float* o_w = (const float*)d_in[28];
    const float* o_b = (const float*)d_in[29];
    const float* attn_ln_g = (const float*)d_in[30];
    const float* attn_ln_b = (const float*)d_in[31];
    const float* f1_w = (const float*)d_in[32];
    const float* f1_b = (const float*)d_in[33];
    const float* f2_w = (const float*)d_in[34];
    const float* f2_b = (const float*)d_in[35];
    const float* ffn_ln_g = (const float*)d_in[36];
    const float* ffn_ln_b = (const float*)d_in[37];
    const float* lin1_w = (const float*)d_in[38];
    const float* lin2_w = (const float*)d_in[39];
    const float* lin3_w = (const float*)d_in[40];
    const float* induction = (const float*)d_in[41];
    const float* gcn_w0 = (const float*)d_in[42];
    const float* gcn_b0 = (const float*)d_in[43];
    const float* gcn_w1 = (const float*)d_in[44];
    const float* gcn_b1 = (const float*)d_in[45];
    const float* cls_w = (const float*)d_in[46];
    const float* cls_b = (const float*)d_in[47];

    float* ws = (float*)d_ws;
    size_t off = 0;
    auto alloc = [&](size_t n) { float* p = ws + off; off += n; return p; };

    float* X    = alloc((size_t)B_ * S_ * D_);        // 1,572,864
    float* PROJ = alloc((size_t)B_ * S_ * D_);
    float* SC   = alloc((size_t)B_ * NH_ * S_ * S_);  // 12,582,912  (also reused as GB later)
    float* CO2  = alloc((size_t)B_ * S_ * D_);
    float* NR   = alloc((size_t)B_ * N_ * D_);
    float* H1   = alloc((size_t)B_ * N_ * H_);
    float* H2   = alloc((size_t)B_ * N_ * H_);
    float* G1   = alloc((size_t)B_ * N_ * H_);
    float* ROOT = alloc((size_t)B_ * N_);
    float* BIL  = alloc((size_t)B_ * N_ * N_);
    float* CS   = alloc((size_t)B_ * N_);
    float* LAP  = alloc((size_t)B_ * N_ * N_);
    float* INV  = alloc((size_t)B_ * N_ * N_);
    float* T1   = alloc((size_t)B_ * N_ * N_);
    float* T2   = alloc((size_t)B_ * N_ * N_);
    float* EDGE = alloc((size_t)B_ * N_ * N_);
    float* DEN  = alloc((size_t)B_ * N_);
    float* GT   = alloc((size_t)B_ * N_ * D_);
    float* X1   = alloc((size_t)B_ * N_ * H_);
    float* GT2  = alloc((size_t)B_ * N_ * H_);
    float* GCN  = alloc((size_t)B_ * N_ * H_);
    float* ENT  = alloc((size_t)B_ * N_ * H_);
    float* QKVBIAS = alloc((size_t)L_ * 2304);

    int* ipool  = (int*)(ws + off); off += 4096;
    int* counts = ipool;
    int* srcidx = ipool + 4;
    int* ncnt   = srcidx + B_ * S_;
    int* nsrc   = ncnt + 4;

    // bf16 (ushort) region
    unsigned short* us = (unsigned short*)(ws + off);
    size_t uoff = 0;
    auto ualloc = [&](size_t n) { unsigned short* p = us + uoff; uoff += n; return p; };

    unsigned short* Xh   = ualloc(1572864);  unsigned short* Xl   = ualloc(1572864);
    unsigned short* QKVh = ualloc((size_t)2048 * 2304);
    unsigned short* QKVl = ualloc((size_t)2048 * 2304);
    unsigned short* Vth  = ualloc(1572864);  unsigned short* Vtl  = ualloc(1572864);
    unsigned short* SCb  = ualloc((size_t)B_ * NH_ * S_ * 1024);   // rows: [512 hi | 512 lo]
    unsigned short* CTXh = ualloc(1572864);  unsigned short* CTXl = ualloc(1572864);
    unsigned short* FFHh = ualloc((size_t)2048 * 3072);
    unsigned short* FFHl = ualloc((size_t)2048 * 3072);
    unsigned short* Wb   = ualloc(14155776);

    float* GB = SC;   // alias: classifier G buffer (needs 5,959,680 <= 12,582,912); SC dead post-encoder

    // ---- qkv bias concat (once) ----
    biascat<<<(L_ * 2304 + 255) / 256, 256, 0, stream>>>(q_b, k_b, v_b, QKVBIAS);

    // ---- embedding + LN ----
    embed_ln<<<B_ * S_, 256, 0, stream>>>(context_idxs, tok_emb, pos_emb, type_emb,
                                          emb_ln_g, emb_ln_b, X, Xh, Xl);

    // ---- 12 encoder layers (bf16 hi/lo split MFMA) ----
    for (int l = 0; l < L_; ++l) {
        wsplit<<<1728, 256, 0, stream>>>(q_w + (size_t)l * D_ * D_, k_w + (size_t)l * D_ * D_,
                                         v_w + (size_t)l * D_ * D_, o_w + (size_t)l * D_ * D_,
                                         f1_w + (size_t)l * D_ * FF_, f2_w + (size_t)l * FF_ * D_, Wb);

        // QKV fused: [2048,768] @ [768,2304] -> pairs [2048,2304]
        mgemm<128, 0, 1><<<dim3(18, 16, 1), 256, 0, stream>>>(
            Xh, Xl, Wb, Wb + 1769472, QKVBIAS + l * 2304,
            nullptr, QKVh, QKVl,
            2048, 2304, 768, 768, 768, 2304, 0, 0, 0, 0, 0, 0, 1, 1.0f);

        // scores: per (b,h): Q[512,64] @ K^T -> fp32 SC, alpha=1/8
        mgemm<128, 0, 0><<<dim3(4, 4, B_ * NH_), 256, 0, stream>>>(
            QKVh, QKVl, QKVh + 768, QKVl + 768, nullptr,
            SC, nullptr, nullptr,
            512, 512, 64, 2304, 2304, 512,
            (long)512 * 2304, 64, (long)512 * 2304, 64,
            (long)NH_ * 512 * 512, (long)512 * 512, NH_, 0.125f);

        softmax512b<<<B_ * NH_ * S_, 256, 0, stream>>>(SC, context_masks, SCb);

        vtrans<<<B_ * NH_ * 8, 256, 0, stream>>>(QKVh, QKVl, Vth, Vtl);

        // PV: per (b,h): P[512,512] @ V[512,64] -> CTX pairs [S,D] head-sliced
        mgemm<64, 0, 1><<<dim3(1, 4, B_ * NH_), 256, 0, stream>>>(
            SCb, SCb + 512, Vth, Vtl, nullptr,
            nullptr, CTXh, CTXl,
            512, 64, 512, 1024, 512, 768,
            (long)NH_ * 512 * 1024, (long)512 * 1024,
            (long)NH_ * 64 * 512, (long)64 * 512,
            (long)512 * 768, 64, NH_, 1.0f);

        // O-proj -> fp32 PROJ
        mgemm<128, 0, 0><<<dim3(6, 16, 1), 256, 0, stream>>>(
            CTXh, CTXl, Wb + 3538944, Wb + 3538944 + 589824, o_b + l * D_,
            PROJ, nullptr, nullptr,
            2048, 768, 768, 768, 768, 768, 0, 0, 0, 0, 0, 0, 1, 1.0f);

        ln_residb<<<B_ * S_, 256, 0, stream>>>(X, Xh, Xl, X, PROJ,
                                               attn_ln_g + l * D_, attn_ln_b + l * D_);

        // FFN1 (gelu) -> pairs
        mgemm<128, 2, 1><<<dim3(24, 16, 1), 256, 0, stream>>>(
            Xh, Xl, Wb + 4718592, Wb + 4718592 + 2359296, f1_b + l * FF_,
            nullptr, FFHh, FFHl,
            2048, 3072, 768, 768, 768, 3072, 0, 0, 0, 0, 0, 0, 1, 1.0f);

        // FFN2 -> fp32 PROJ
        mgemm<128, 0, 0><<<dim3(6, 16, 1), 256, 0, stream>>>(
            FFHh, FFHl, Wb + 9437184, Wb + 9437184 + 2359296, f2_b + l * D_,
            PROJ, nullptr, nullptr,
            2048, 768, 3072, 3072, 3072, 768, 0, 0, 0, 0, 0, 0, 1, 1.0f);

        ln_residb<<<B_ * S_, 256, 0, stream>>>(X, Xh, Xl, X, PROJ,
                                               ffn_ln_g + l * D_, ffn_ln_b + l * D_);
    }

    // ---- start-token gather ----
    scan_starts<<<B_, 512, 0, stream>>>(context_starts, counts, srcidx);
    fill_co<<<B_ * S_, 256, 0, stream>>>(X, CO2, counts, srcidx);

    // ---- node_rep = node_mapping @ co ----
    launch_gemm(stream, 0, 0, node_mapping, CO2, nullptr, nullptr, NR,
                N_, D_, S_, S_, D_, D_,
                (long)N_ * S_, 0, (long)S_ * D_, 0, (long)N_ * D_, 0,
                B_, 1, 1.0f);

    // ---- h1, h2, g1, root, bil ----
    launch_gemm(stream, 1, 0, NR, lin1_w, nullptr, nullptr, H1,
                B_ * N_, H_, D_, D_, H_, H_, 0, 0, 0, 0, 0, 0, 1, 1, 1.0f);
    launch_gemm(stream, 1, 0, NR, lin2_w, nullptr, nullptr, H2,
                B_ * N_, H_, D_, D_, H_, H_, 0, 0, 0, 0, 0, 0, 1, 1, 1.0f);
    launch_gemm(stream, 0, 0, H1, induction, nullptr, nullptr, G1,
                B_ * N_, H_, H_, H_, H_, H_, 0, 0, 0, 0, 0, 0, 1, 1, 1.0f);
    rowdot<<<B_ * N_, 256, 0, stream>>>(NR, lin3_w, ROOT, D_);
    launch_gemm(stream, 0, 1, G1, H2, nullptr, nullptr, BIL,
                N_, N_, H_, H_, H_, N_,
                (long)N_ * H_, 0, (long)N_ * H_, 0, (long)N_ * N_, 0,
                B_, 1, 1.0f);

    // ---- matrix-tree ----
    p_exp<<<(B_ * N_ * N_) / 256, 256, 0, stream>>>(BIL);
    colsum_k<<<B_, 128, 0, stream>>>(BIL, CS);
    lap_build<<<(B_ * N_ * N_) / 256, 256, 0, stream>>>(BIL, CS, ROOT, LAP);
    invert128d<<<B_, 1024, 0, stream>>>(LAP, INV);
    launch_gemm(stream, 0, 0, BIL, INV, nullptr, nullptr, T1,
                N_, N_, N_, N_, N_, N_,
                (long)N_ * N_, 0, (long)N_ * N_, 0, (long)N_ * N_, 0, B_, 1, 1.0f);
    launch_gemm(stream, 0, 1, BIL, INV, nullptr, nullptr, T2,
                N_, N_, N_, N_, N_, N_,
                (long)N_ * N_, 0, (long)N_ * N_, 0, (long)N_ * N_, 0, B_, 1, 1.0f);
    edge_build<<<(B_ * N_ * N_) / 256, 256, 0, stream>>>(T1, T2, EDGE);
    denom_k<<<B_, 128, 0, stream>>>(EDGE, DEN);

    // ---- GCN layer 0 ----
    launch_gemm(stream, 0, 0, EDGE, NR, nullptr, nullptr, GT,
                N_, D_, N_, N_, D_, D_,
                (long)N_ * N_, 0, (long)N_ * D_, 0, (long)N_ * D_, 0, B_, 1, 1.0f);
    addv<<<(B_ * N_ * D_) / 256, 256, 0, stream>>>(GT, NR, B_ * N_ * D_);
    launch_gemm(stream, 3, 0, GT, gcn_w0, gcn_b0, DEN, X1,
                B_ * N_, H_, D_, D_, H_, H_, 0, 0, 0, 0, 0, 0, 1, 1, 1.0f);

    // ---- GCN layer 1 ----
    launch_gemm(stream, 0, 0, EDGE, X1, nullptr, nullptr, GT2,
                N_, H_, N_, N_, H_, H_,
                (long)N_ * N_, 0, (long)N_ * H_, 0, (long)N_ * H_, 0, B_, 1, 1.0f);
    addv<<<(B_ * N_ * H_) / 256, 256, 0, stream>>>(GT2, X1, B_ * N_ * H_);
    launch_gemm(stream, 3, 0, GT2, gcn_w1, gcn_b1, DEN, GCN,
                B_ * N_, H_, H_, H_, H_, H_, 0, 0, 0, 0, 0, 0, 1, 1, 1.0f);

    // ---- entity gather ----
    scan_nodes<<<B_, 128, 0, stream>>>(node_mask, ncnt, nsrc);
    fill_ent<<<B_ * N_, 128, 0, stream>>>(GCN, ENT, ncnt, nsrc);

    // ---- classifier ----
    launch_gemm(stream, 0, 0, ENT, cls_w, nullptr, nullptr, GB,
                B_ * N_, H_, H_, H_, R_ * H_, R_ * H_,
                0, 0, (long)H_, 0, (long)H_, 0,
                R_, 1, 1.0f);
    pred_kernel<<<B_ * N_, 256, 0, stream>>>(GB, ENT, cls_b, (float*)d_out);
}